// Round 9
// baseline (192.981 us; speedup 1.0000x reference)
//
#include <hip/hip_runtime.h>

typedef __bf16 bf16x8 __attribute__((ext_vector_type(8)));
typedef float f32x4 __attribute__((ext_vector_type(4)));

#define DEV __device__ __forceinline__

DEV unsigned short f2bf(float f) {
  union { float f; unsigned u; } x; x.f = f;
  unsigned r = x.u + 0x7FFFu + ((x.u >> 16) & 1u);  // RNE
  return (unsigned short)(r >> 16);
}
DEV float bf2f(unsigned short h) {
  union { unsigned u; float f; } x; x.u = ((unsigned)h) << 16;
  return x.f;
}

typedef __attribute__((address_space(3))) void* lds_vp;
typedef const __attribute__((address_space(1))) void* gbl_vp;
DEV void load_lds16(const unsigned short* gp, void* lp) {
  __builtin_amdgcn_global_load_lds((gbl_vp)(const void*)gp, (lds_vp)lp, 16, 0, 0);
}

// ---- fused ingest (inputs f32): convert x/rel/bo, transpose Wq|Wkv|Wo -----
__global__ __launch_bounds__(256)
void prep_k(const float* __restrict__ x, const float* __restrict__ rel,
            const float* __restrict__ bo, const float* __restrict__ Wq,
            const float* __restrict__ Wkv, const float* __restrict__ Wo,
            unsigned short* __restrict__ xb, unsigned short* __restrict__ relb,
            unsigned short* __restrict__ bob, unsigned short* __restrict__ WqkvT,
            unsigned short* __restrict__ WoT) {
  __shared__ unsigned short tile[32][33];
  const int bid = blockIdx.x, tid = threadIdx.x;
  if (bid < 2114) {
    const float* src; unsigned short* dst; long base; long n;
    if (bid < 2048)      { src = x;   dst = xb;   base = (long)bid * 1024;          n = 2097152; }
    else if (bid < 2113) { src = rel; dst = relb; base = (long)(bid - 2048) * 1024; n = 65600; }
    else                 { src = bo;  dst = bob;  base = 0;                          n = 1024; }
    long i = base + tid * 4;
    if (i < n) {
      float4 v = *(const float4*)&src[i];
      unsigned long long u = (unsigned long long)f2bf(v.x)
                           | ((unsigned long long)f2bf(v.y) << 16)
                           | ((unsigned long long)f2bf(v.z) << 32)
                           | ((unsigned long long)f2bf(v.w) << 48);
      *(unsigned long long*)&dst[i] = u;
    }
  } else {
    int id = bid - 2114;
    const float* src; unsigned short* dst; const int R = 1024; int C, txt, tyt;
    if (id < 1024)      { src = Wq;  dst = WqkvT;           C = 1024; txt = id & 31; tyt = id >> 5; }
    else if (id < 3072) { int l = id - 1024; src = Wkv; dst = WqkvT + 1048576; C = 2048; txt = l & 63; tyt = l >> 6; }
    else                { int l = id - 3072; src = Wo;  dst = WoT;             C = 1024; txt = l & 31; tyt = l >> 5; }
    int c0 = txt * 32, r0 = tyt * 32;
    int tx = tid & 31, ty = tid >> 5;
    #pragma unroll
    for (int i = 0; i < 4; ++i)
      tile[ty + i * 8][tx] = f2bf(src[(size_t)(r0 + ty + i * 8) * C + c0 + tx]);
    __syncthreads();
    #pragma unroll
    for (int i = 0; i < 4; ++i)
      dst[(size_t)(c0 + ty + i * 8) * R + r0 + tx] = tile[tx][ty + i * 8];
  }
}

// ---------------- GEMM qkv = x @ WqkvT^T --------------------------------
// q: *0.125, [b,h,n,d]; k: [b,h,n,d]; v: transposed in-kernel -> vT[b,h,d,n].
__global__ __launch_bounds__(256)
void gemm_qkv(const unsigned short* __restrict__ A,
              const unsigned short* __restrict__ Bt,
              unsigned short* __restrict__ o0,   // q [b,h,n,d]
              unsigned short* __restrict__ o1,   // k [b,h,n,d]
              unsigned short* __restrict__ o2) { // vT [b,h,d,n]
  __shared__ __align__(16) unsigned short As[128][32];
  __shared__ __align__(16) unsigned short Bs[128][32];
  __shared__ unsigned short tbuf[128][68];   // v-transpose staging (17 KB)
  const int tid  = threadIdx.x;
  const int lane = tid & 63, wave = tid >> 6;
  const int q15  = lane & 15, quad = lane >> 4;
  const int wr = wave >> 1, wc = wave & 1;
  const int m0 = blockIdx.y * 128, n0 = blockIdx.x * 128;
  const int K = 1024;
  const int lrow = lane >> 2, lkc = (lane & 3) * 8;

  f32x4 acc[4][4] = {};
  for (int k0 = 0; k0 < K; k0 += 32) {
    __syncthreads();
    #pragma unroll
    for (int t = 0; t < 2; ++t) {
      int r0 = wave * 32 + t * 16;
      load_lds16(&A[(size_t)(m0 + r0 + lrow) * K + k0 + lkc], &As[r0][0]);
      load_lds16(&Bt[(size_t)(n0 + r0 + lrow) * K + k0 + lkc], &Bs[r0][0]);
    }
    __syncthreads();
    bf16x8 af[4], bfr[4];
    #pragma unroll
    for (int i = 0; i < 4; ++i) {
      af[i]  = *(const bf16x8*)&As[wr * 64 + i * 16 + q15][quad * 8];
      bfr[i] = *(const bf16x8*)&Bs[wc * 64 + i * 16 + q15][quad * 8];
    }
    #pragma unroll
    for (int i = 0; i < 4; ++i)
      #pragma unroll
      for (int j = 0; j < 4; ++j)
        acc[i][j] = __builtin_amdgcn_mfma_f32_16x16x32_bf16(af[i], bfr[j], acc[i][j], 0, 0, 0);
  }

  const int b = m0 >> 10, nn0 = m0 & 1023;
  if (n0 < 2048) {
    // q / k epilogue (coalesced [b,h,n,d] stores)
    #pragma unroll
    for (int i = 0; i < 4; ++i)
      #pragma unroll
      for (int j = 0; j < 4; ++j)
        #pragma unroll
        for (int r = 0; r < 4; ++r) {
          int row = m0 + wr * 64 + i * 16 + quad * 4 + r;
          int col = n0 + wc * 64 + j * 16 + q15;
          float v = acc[i][j][r];
          int nn = row & 1023;
          unsigned short* dst; int c = col; float sc = 1.f;
          if (col < 1024) { dst = o0; sc = 0.125f; }
          else            { dst = o1; c = col - 1024; }
          int h = c >> 6, dd = c & 63;
          dst[((size_t)((row >> 10) * 16 + h) * 1024 + nn) * 64 + dd] = f2bf(v * sc);
        }
  } else {
    // v epilogue: transpose 128 rows x (2 heads x 64 d) via LDS, store vT[b,h,d,n]
    const int hp = (n0 - 2048) >> 6;  // head pair base
    #pragma unroll
    for (int hh = 0; hh < 2; ++hh) {
      __syncthreads();
      if (wc == hh) {
        #pragma unroll
        for (int i = 0; i < 4; ++i)
          #pragma unroll
          for (int j = 0; j < 4; ++j)
            #pragma unroll
            for (int r = 0; r < 4; ++r)
              tbuf[wr * 64 + i * 16 + quad * 4 + r][j * 16 + q15] = f2bf(acc[i][j][r]);
      }
      __syncthreads();
      // cooperative coalesced store: 64 d x 128 n
      const int bh = b * 16 + hp + hh;
      const int dl = tid >> 3, nb = (tid & 7) * 8;
      #pragma unroll
      for (int p = 0; p < 2; ++p)
        #pragma unroll
        for (int s = 0; s < 2; ++s) {
          int d = dl + p * 32, n = nb + s * 64;
          union { uint4 v; unsigned short us[8]; } t;
          #pragma unroll
          for (int e = 0; e < 8; ++e) t.us[e] = tbuf[n + e][d];
          *(uint4*)&o2[((size_t)bh * 64 + d) * 1024 + nn0 + n] = t.v;
        }
    }
  }
}

// ---- swizzled tile staging: [64 rows][64 shorts], chunk ^= row&7 ----------
DEV void stage16(const unsigned short* gbase, size_t gstride,
                 unsigned short* lbase, int r0, int lane) {
  #pragma unroll
  for (int t = 0; t < 2; ++t) {
    int r = r0 + t * 8 + (lane >> 3);
    int lc = (lane & 7) ^ (r & 7);
    load_lds16(&gbase[(size_t)r * gstride + lc * 8], &lbase[(size_t)(r0 + t * 8) * 64]);
  }
}
DEV bf16x8 read_swz(const unsigned short* buf, int row, int lc) {
  int pc = lc ^ (row & 7);
  return *(const bf16x8*)&buf[row * 64 + pc * 8];
}

// ---------------- flash attention: no split, dbuf, shuffle-T, swz-P --------
// grid (x=bh 32 -> XCD locality, y=i-tile 16); 4 waves x 16 Q-rows; 16 jt.
// LDS = 16K(K dbuf) + 16K(V dbuf) + 8K(P) = 40 KB. 1 barrier/jt.
__global__ __launch_bounds__(256)
void flash_attn(const unsigned short* __restrict__ q_ws,   // pre-scaled .125
                const unsigned short* __restrict__ k_ws,
                const unsigned short* __restrict__ vt_ws,  // [bh][64][1024]
                const unsigned short* __restrict__ rel,    // [1025][64]
                unsigned short* __restrict__ ao) {         // [2048][1024]
  __shared__ __align__(16) unsigned short Kbuf[2][64 * 64];
  __shared__ __align__(16) unsigned short Vbuf[2][64 * 64];
  __shared__ __align__(16) unsigned short P_lds[4][16 * 64];  // XOR-8 swizzled

  const int tid  = threadIdx.x;
  const int lane = tid & 63, w = tid >> 6;
  const int q15  = lane & 15, quad = lane >> 4;
  const int bh = blockIdx.x;
  const int ib = blockIdx.y * 64 + w * 16;

  const unsigned short* qp = q_ws  + (size_t)bh * 1024 * 64;
  const unsigned short* kp = k_ws  + (size_t)bh * 1024 * 64;
  const unsigned short* tp = vt_ws + (size_t)bh * 64 * 1024;

  bf16x8 aq[2];
  #pragma unroll
  for (int ks = 0; ks < 2; ++ks)
    aq[ks] = *(const bf16x8*)&qp[(size_t)(ib + q15) * 64 + ks * 32 + quad * 8];

  f32x4 o[4] = {};
  float l_i[4] = {0.f, 0.f, 0.f, 0.f};

  // prologue: stage tile 0
  stage16(kp, 64, &Kbuf[0][0], w * 16, lane);
  stage16(tp, 1024, &Vbuf[0][0], w * 16, lane);

  for (int jt = 0; jt < 16; ++jt) {
    const int j0 = jt * 64, cur = jt & 1;
    __syncthreads();  // buf[cur] staged; prev readers of buf[cur^1] done
    if (jt + 1 < 16) {
      stage16(kp + (size_t)(j0 + 64) * 64, 64, &Kbuf[cur ^ 1][0], w * 16, lane);
      stage16(tp + (j0 + 64), 1024, &Vbuf[cur ^ 1][0], w * 16, lane);
    }

    // Q K^T
    f32x4 accS[4] = {};
    #pragma unroll
    for (int ks = 0; ks < 2; ++ks)
      #pragma unroll
      for (int cb = 0; cb < 4; ++cb) {
        bf16x8 bk = read_swz(&Kbuf[cur][0], cb * 16 + q15, ks * 4 + quad);
        accS[cb] = __builtin_amdgcn_mfma_f32_16x16x32_bf16(aq[ks], bk, accS[cb], 0, 0, 0);
      }
    // positional band T[16][80] in MFMA C-layout registers
    int tb = ib - j0 + 512 - 63;
    f32x4 accT[5] = {};
    #pragma unroll
    for (int ks = 0; ks < 2; ++ks)
      #pragma unroll
      for (int ub = 0; ub < 5; ++ub) {
        int trow = tb + ub * 16 + q15;
        trow = trow < 0 ? 0 : (trow > 1024 ? 1024 : trow);
        bf16x8 br = *(const bf16x8*)&rel[(size_t)trow * 64 + ks * 32 + quad * 8];
        accT[ub] = __builtin_amdgcn_mfma_f32_16x16x32_bf16(aq[ks], br, accT[ub], 0, 0, 0);
      }

    // softmax numerators: gather T via quad-group shuffles, exp, stage P
    #pragma unroll
    for (int r = 0; r < 4; ++r) {
      const int dl = quad * 4 + r;
      const int src = quad * 16 + ((15 + dl - q15) & 15);
      float tv[5];
      #pragma unroll
      for (int ub = 0; ub < 5; ++ub)
        tv[ub] = __shfl(accT[ub][r], src, 64);
      const bool hi = (q15 < dl);  // (63+dl-q15) >= 64
      #pragma unroll
      for (int cb = 0; cb < 4; ++cb) {
        float tval = hi ? tv[4 - cb] : tv[3 - cb];
        float s = accS[cb][r] + tval;
        float p = exp2f(s * 1.44269504f - 64.f);
        l_i[r] += p;
        int k = cb * 16 + q15;
        P_lds[w][dl * 64 + ((((k >> 3) ^ (dl & 7)) << 3) | (k & 7))] = f2bf(p);
      }
    }

    // O += P @ V (P per-wave swizzled LDS; V^T swizzled)
    #pragma unroll
    for (int ks = 0; ks < 2; ++ks) {
      bf16x8 ap = *(const bf16x8*)&P_lds[w][q15 * 64 + (((ks * 4 + quad) ^ (q15 & 7)) << 3)];
      #pragma unroll
      for (int db = 0; db < 4; ++db) {
        bf16x8 bv = read_swz(&Vbuf[cur][0], db * 16 + q15, ks * 4 + quad);
        o[db] = __builtin_amdgcn_mfma_f32_16x16x32_bf16(ap, bv, o[db], 0, 0, 0);
      }
    }
  }

  // l: reduce across the 16 lanes of each quad group
  #pragma unroll
  for (int r = 0; r < 4; ++r) {
    #pragma unroll
    for (int off = 1; off < 16; off <<= 1)
      l_i[r] += __shfl_xor(l_i[r], off, 64);
    l_i[r] = 1.f / (l_i[r] + 1e-30f);
  }

  const int b = bh >> 4, h = bh & 15;
  #pragma unroll
  for (int db = 0; db < 4; ++db)
    #pragma unroll
    for (int r = 0; r < 4; ++r) {
      int row = ib + quad * 4 + r;
      ao[((size_t)(b * 1024 + row)) * 1024 + h * 64 + db * 16 + q15] =
          f2bf(o[db][r] * l_i[r]);
    }
}

// ---------------- GEMM out = ao @ WoT^T + bo (f32 out), 128x64 tiles -------
__global__ __launch_bounds__(256)
void gemm_out(const unsigned short* __restrict__ A,
              const unsigned short* __restrict__ Bt,
              const unsigned short* __restrict__ bias,
              float* __restrict__ fo) {
  __shared__ __align__(16) unsigned short As[128][32];
  __shared__ __align__(16) unsigned short Bs[64][32];
  const int tid  = threadIdx.x;
  const int lane = tid & 63, w = tid >> 6;
  const int q15  = lane & 15, quad = lane >> 4;
  const int m0 = blockIdx.y * 128, n0 = blockIdx.x * 64;
  const int K = 1024, N = 1024;
  const int lrow = lane >> 2, lkc = (lane & 3) * 8;

  f32x4 acc[2][4] = {};
  for (int k0 = 0; k0 < K; k0 += 32) {
    __syncthreads();
    #pragma unroll
    for (int t = 0; t < 2; ++t) {
      int r0 = w * 32 + t * 16;
      load_lds16(&A[(size_t)(m0 + r0 + lrow) * K + k0 + lkc], &As[r0][0]);
    }
    load_lds16(&Bt[(size_t)(n0 + w * 16 + lrow) * K + k0 + lkc], &Bs[w * 16][0]);
    __syncthreads();
    bf16x8 af[2], bfr[4];
    #pragma unroll
    for (int i = 0; i < 2; ++i)
      af[i] = *(const bf16x8*)&As[w * 32 + i * 16 + q15][quad * 8];
    #pragma unroll
    for (int j = 0; j < 4; ++j)
      bfr[j] = *(const bf16x8*)&Bs[j * 16 + q15][quad * 8];
    #pragma unroll
    for (int i = 0; i < 2; ++i)
      #pragma unroll
      for (int j = 0; j < 4; ++j)
        acc[i][j] = __builtin_amdgcn_mfma_f32_16x16x32_bf16(af[i], bfr[j], acc[i][j], 0, 0, 0);
  }
  #pragma unroll
  for (int i = 0; i < 2; ++i)
    #pragma unroll
    for (int j = 0; j < 4; ++j)
      #pragma unroll
      for (int r = 0; r < 4; ++r) {
        int row = m0 + w * 32 + i * 16 + quad * 4 + r;
        int col = n0 + j * 16 + q15;
        fo[(size_t)row * N + col] = acc[i][j][r] + bf2f(bias[col]);
      }
}

// ---------------------------------------------------------------------------
extern "C" void kernel_launch(void* const* d_in, const int* in_sizes, int n_in,
                              void* d_out, int out_size, void* d_ws, size_t ws_size,
                              hipStream_t stream) {
  (void)in_sizes; (void)n_in; (void)out_size; (void)ws_size;
  const float* x   = (const float*)d_in[0];
  const float* Wq  = (const float*)d_in[1];
  const float* Wkv = (const float*)d_in[2];
  const float* Wo  = (const float*)d_in[3];
  const float* bo  = (const float*)d_in[4];
  const float* rel = (const float*)d_in[5];
  float* out = (float*)d_out;

  unsigned short* ws = (unsigned short*)d_ws;
  unsigned short* WoT   = ws;                      // 1,048,576
  unsigned short* relb  = WoT   + 1048576;         // 65,664 reserved
  unsigned short* bob   = relb  + 65664;           // 1,088 reserved
  unsigned short* q_ws  = bob   + 1088;            // 2,097,152
  unsigned short* k_ws  = q_ws  + 2097152;         // 2,097,152
  unsigned short* vT    = k_ws  + 2097152;         // 2,097,152
  unsigned short* WqkvT = vT    + 2097152;         // 3,145,728 (dead after gemm_qkv)
  unsigned short* xb    = WqkvT + 3145728;         // 2,097,152 (dead after gemm_qkv)
  unsigned short* ao    = WqkvT;                   // alias

  prep_k<<<6210, 256, 0, stream>>>(x, rel, bo, Wq, Wkv, Wo,
                                   xb, relb, bob, WqkvT, WoT);
  gemm_qkv<<<dim3(24, 16), 256, 0, stream>>>(xb, WqkvT, q_ws, k_ws, vT);
  flash_attn<<<dim3(32, 16), 256, 0, stream>>>(q_ws, k_ws, vT, relb, ao);
  gemm_out<<<dim3(16, 16), 256, 0, stream>>>(ao, WoT, bob, out);
}

// Round 10
// 187.942 us; speedup vs baseline: 1.0268x; 1.0268x over previous
//
#include <hip/hip_runtime.h>

typedef __bf16 bf16x8 __attribute__((ext_vector_type(8)));
typedef float f32x4 __attribute__((ext_vector_type(4)));

#define DEV __device__ __forceinline__

DEV unsigned short f2bf(float f) {
  union { float f; unsigned u; } x; x.f = f;
  unsigned r = x.u + 0x7FFFu + ((x.u >> 16) & 1u);  // RNE
  return (unsigned short)(r >> 16);
}
DEV float bf2f(unsigned short h) {
  union { unsigned u; float f; } x; x.u = ((unsigned)h) << 16;
  return x.f;
}
DEV unsigned short bfc(float f) {  // hw cvt (RNE) — hot-loop variant
  union { __bf16 b; unsigned short u; } c; c.b = (__bf16)f; return c.u;
}

typedef __attribute__((address_space(3))) void* lds_vp;
typedef const __attribute__((address_space(1))) void* gbl_vp;
DEV void load_lds16(const unsigned short* gp, void* lp) {
  __builtin_amdgcn_global_load_lds((gbl_vp)(const void*)gp, (lds_vp)lp, 16, 0, 0);
}

// ---- fused ingest (inputs f32): convert x/rel/bo, transpose Wq|Wkv|Wo -----
__global__ __launch_bounds__(256)
void prep_k(const float* __restrict__ x, const float* __restrict__ rel,
            const float* __restrict__ bo, const float* __restrict__ Wq,
            const float* __restrict__ Wkv, const float* __restrict__ Wo,
            unsigned short* __restrict__ xb, unsigned short* __restrict__ relb,
            unsigned short* __restrict__ bob, unsigned short* __restrict__ WqkvT,
            unsigned short* __restrict__ WoT) {
  __shared__ unsigned short tile[32][33];
  const int bid = blockIdx.x, tid = threadIdx.x;
  if (bid < 2114) {
    const float* src; unsigned short* dst; long base; long n;
    if (bid < 2048)      { src = x;   dst = xb;   base = (long)bid * 1024;          n = 2097152; }
    else if (bid < 2113) { src = rel; dst = relb; base = (long)(bid - 2048) * 1024; n = 65600; }
    else                 { src = bo;  dst = bob;  base = 0;                          n = 1024; }
    long i = base + tid * 4;
    if (i < n) {
      float4 v = *(const float4*)&src[i];
      unsigned long long u = (unsigned long long)f2bf(v.x)
                           | ((unsigned long long)f2bf(v.y) << 16)
                           | ((unsigned long long)f2bf(v.z) << 32)
                           | ((unsigned long long)f2bf(v.w) << 48);
      *(unsigned long long*)&dst[i] = u;
    }
  } else {
    int id = bid - 2114;
    const float* src; unsigned short* dst; const int R = 1024; int C, txt, tyt;
    if (id < 1024)      { src = Wq;  dst = WqkvT;           C = 1024; txt = id & 31; tyt = id >> 5; }
    else if (id < 3072) { int l = id - 1024; src = Wkv; dst = WqkvT + 1048576; C = 2048; txt = l & 63; tyt = l >> 6; }
    else                { int l = id - 3072; src = Wo;  dst = WoT;             C = 1024; txt = l & 31; tyt = l >> 5; }
    int c0 = txt * 32, r0 = tyt * 32;
    int tx = tid & 31, ty = tid >> 5;
    #pragma unroll
    for (int i = 0; i < 4; ++i)
      tile[ty + i * 8][tx] = f2bf(src[(size_t)(r0 + ty + i * 8) * C + c0 + tx]);
    __syncthreads();
    #pragma unroll
    for (int i = 0; i < 4; ++i)
      dst[(size_t)(c0 + ty + i * 8) * R + r0 + tx] = tile[tx][ty + i * 8];
  }
}

// ---------------- GEMM qkv = x @ WqkvT^T --------------------------------
// q: *0.125, [b,h,n,d]; k: [b,h,n,d]; v: transposed in-kernel -> vT[b,h,d,n].
__global__ __launch_bounds__(256)
void gemm_qkv(const unsigned short* __restrict__ A,
              const unsigned short* __restrict__ Bt,
              unsigned short* __restrict__ o0,   // q [b,h,n,d]
              unsigned short* __restrict__ o1,   // k [b,h,n,d]
              unsigned short* __restrict__ o2) { // vT [b,h,d,n]
  __shared__ __align__(16) unsigned short As[128][32];
  __shared__ __align__(16) unsigned short Bs[128][32];
  __shared__ unsigned short tbuf[128][68];   // v-transpose staging (17 KB)
  const int tid  = threadIdx.x;
  const int lane = tid & 63, wave = tid >> 6;
  const int q15  = lane & 15, quad = lane >> 4;
  const int wr = wave >> 1, wc = wave & 1;
  const int m0 = blockIdx.y * 128, n0 = blockIdx.x * 128;
  const int K = 1024;
  const int lrow = lane >> 2, lkc = (lane & 3) * 8;

  f32x4 acc[4][4] = {};
  for (int k0 = 0; k0 < K; k0 += 32) {
    __syncthreads();
    #pragma unroll
    for (int t = 0; t < 2; ++t) {
      int r0 = wave * 32 + t * 16;
      load_lds16(&A[(size_t)(m0 + r0 + lrow) * K + k0 + lkc], &As[r0][0]);
      load_lds16(&Bt[(size_t)(n0 + r0 + lrow) * K + k0 + lkc], &Bs[r0][0]);
    }
    __syncthreads();
    bf16x8 af[4], bfr[4];
    #pragma unroll
    for (int i = 0; i < 4; ++i) {
      af[i]  = *(const bf16x8*)&As[wr * 64 + i * 16 + q15][quad * 8];
      bfr[i] = *(const bf16x8*)&Bs[wc * 64 + i * 16 + q15][quad * 8];
    }
    #pragma unroll
    for (int i = 0; i < 4; ++i)
      #pragma unroll
      for (int j = 0; j < 4; ++j)
        acc[i][j] = __builtin_amdgcn_mfma_f32_16x16x32_bf16(af[i], bfr[j], acc[i][j], 0, 0, 0);
  }

  const int b = m0 >> 10, nn0 = m0 & 1023;
  if (n0 < 2048) {
    // q / k epilogue (coalesced [b,h,n,d] stores)
    #pragma unroll
    for (int i = 0; i < 4; ++i)
      #pragma unroll
      for (int j = 0; j < 4; ++j)
        #pragma unroll
        for (int r = 0; r < 4; ++r) {
          int row = m0 + wr * 64 + i * 16 + quad * 4 + r;
          int col = n0 + wc * 64 + j * 16 + q15;
          float v = acc[i][j][r];
          int nn = row & 1023;
          unsigned short* dst; int c = col; float sc = 1.f;
          if (col < 1024) { dst = o0; sc = 0.125f; }
          else            { dst = o1; c = col - 1024; }
          int h = c >> 6, dd = c & 63;
          dst[((size_t)((row >> 10) * 16 + h) * 1024 + nn) * 64 + dd] = f2bf(v * sc);
        }
  } else {
    // v epilogue: transpose 128 rows x (2 heads x 64 d) via LDS, store vT[b,h,d,n]
    const int hp = (n0 - 2048) >> 6;  // head pair base
    #pragma unroll
    for (int hh = 0; hh < 2; ++hh) {
      __syncthreads();
      if (wc == hh) {
        #pragma unroll
        for (int i = 0; i < 4; ++i)
          #pragma unroll
          for (int j = 0; j < 4; ++j)
            #pragma unroll
            for (int r = 0; r < 4; ++r)
              tbuf[wr * 64 + i * 16 + quad * 4 + r][j * 16 + q15] = f2bf(acc[i][j][r]);
      }
      __syncthreads();
      // cooperative coalesced store: 64 d x 128 n
      const int bh = b * 16 + hp + hh;
      const int dl = tid >> 3, nb = (tid & 7) * 8;
      #pragma unroll
      for (int p = 0; p < 2; ++p)
        #pragma unroll
        for (int s = 0; s < 2; ++s) {
          int d = dl + p * 32, n = nb + s * 64;
          union { uint4 v; unsigned short us[8]; } t;
          #pragma unroll
          for (int e = 0; e < 8; ++e) t.us[e] = tbuf[n + e][d];
          *(uint4*)&o2[((size_t)bh * 64 + d) * 1024 + nn0 + n] = t.v;
        }
    }
  }
}

// ---- swizzled tile staging: [64 rows][64 shorts], chunk ^= row&7 ----------
DEV void stage16(const unsigned short* gbase, size_t gstride,
                 unsigned short* lbase, int r0, int lane) {
  #pragma unroll
  for (int t = 0; t < 2; ++t) {
    int r = r0 + t * 8 + (lane >> 3);
    int lc = (lane & 7) ^ (r & 7);
    load_lds16(&gbase[(size_t)r * gstride + lc * 8], &lbase[(size_t)(r0 + t * 8) * 64]);
  }
}
DEV bf16x8 read_swz(const unsigned short* buf, int row, int lc) {
  int pc = lc ^ (row & 7);
  return *(const bf16x8*)&buf[row * 64 + pc * 8];
}

// ---------------- flash attention: dbuf, f32 LDS-T (stride 84), XOR-P ------
// grid (x=bh 32 -> XCD locality, y=i-tile 16); 4 waves x 16 Q-rows; 16 jt.
// T roundtrip via per-wave LDS (beats bpermute-gather: R6 vs R9 = 54 vs 62).
// Stride 84 f32: quad row-starts at banks {0,16,0,16}; every (r,cb) access is
// 16 consecutive f32 x 2 quad-pairs = 2 lanes/bank = conflict-free (m136).
__global__ __launch_bounds__(256)
void flash_attn(const unsigned short* __restrict__ q_ws,   // pre-scaled .125
                const unsigned short* __restrict__ k_ws,
                const unsigned short* __restrict__ vt_ws,  // [bh][64][1024]
                const unsigned short* __restrict__ rel,    // [1025][64]
                unsigned short* __restrict__ ao) {         // [2048][1024]
  __shared__ __align__(16) unsigned short Kbuf[2][64 * 64];
  __shared__ __align__(16) unsigned short Vbuf[2][64 * 64];
  __shared__ __align__(16) unsigned short P_lds[4][16 * 64];  // XOR-8 swizzled
  __shared__ __align__(16) float T_lds[4][16][84];            // f32 band

  const int tid  = threadIdx.x;
  const int lane = tid & 63, w = tid >> 6;
  const int q15  = lane & 15, quad = lane >> 4;
  const int bh = blockIdx.x;
  const int ib = blockIdx.y * 64 + w * 16;

  const unsigned short* qp = q_ws  + (size_t)bh * 1024 * 64;
  const unsigned short* kp = k_ws  + (size_t)bh * 1024 * 64;
  const unsigned short* tp = vt_ws + (size_t)bh * 64 * 1024;

  bf16x8 aq[2];
  #pragma unroll
  for (int ks = 0; ks < 2; ++ks)
    aq[ks] = *(const bf16x8*)&qp[(size_t)(ib + q15) * 64 + ks * 32 + quad * 8];

  f32x4 o[4] = {};
  float l_i[4] = {0.f, 0.f, 0.f, 0.f};

  // prologue: stage tile 0
  stage16(kp, 64, &Kbuf[0][0], w * 16, lane);
  stage16(tp, 1024, &Vbuf[0][0], w * 16, lane);

  for (int jt = 0; jt < 16; ++jt) {
    const int j0 = jt * 64, cur = jt & 1;
    __syncthreads();  // buf[cur] staged; prev readers of buf[cur^1] done
    if (jt + 1 < 16) {
      stage16(kp + (size_t)(j0 + 64) * 64, 64, &Kbuf[cur ^ 1][0], w * 16, lane);
      stage16(tp + (j0 + 64), 1024, &Vbuf[cur ^ 1][0], w * 16, lane);
    }

    // Q K^T
    f32x4 accS[4] = {};
    #pragma unroll
    for (int ks = 0; ks < 2; ++ks)
      #pragma unroll
      for (int cb = 0; cb < 4; ++cb) {
        bf16x8 bk = read_swz(&Kbuf[cur][0], cb * 16 + q15, ks * 4 + quad);
        accS[cb] = __builtin_amdgcn_mfma_f32_16x16x32_bf16(aq[ks], bk, accS[cb], 0, 0, 0);
      }
    // positional band T[16][80]: C-layout row=quad*4+r (Q-row), col=band u
    int tb = ib - j0 + 512 - 63;
    f32x4 accT[5] = {};
    #pragma unroll
    for (int ks = 0; ks < 2; ++ks)
      #pragma unroll
      for (int ub = 0; ub < 5; ++ub) {
        int trow = tb + ub * 16 + q15;
        trow = trow < 0 ? 0 : (trow > 1024 ? 1024 : trow);
        bf16x8 br = *(const bf16x8*)&rel[(size_t)trow * 64 + ks * 32 + quad * 8];
        accT[ub] = __builtin_amdgcn_mfma_f32_16x16x32_bf16(aq[ks], br, accT[ub], 0, 0, 0);
      }
    #pragma unroll
    for (int ub = 0; ub < 5; ++ub)
      #pragma unroll
      for (int r = 0; r < 4; ++r)
        T_lds[w][quad * 4 + r][ub * 16 + q15] = accT[ub][r];
    // per-wave LDS: no barrier; compiler inserts lgkmcnt

    // p = exp2(s*log2e - 64); accumulate l per-lane; stage P (XOR swizzle)
    #pragma unroll
    for (int r = 0; r < 4; ++r) {
      const int dl = quad * 4 + r;
      #pragma unroll
      for (int cb = 0; cb < 4; ++cb) {
        int dj = cb * 16 + q15;
        float s = accS[cb][r] + T_lds[w][dl][63 + dl - dj];
        float p = exp2f(fmaf(s, 1.44269504f, -64.f));
        l_i[r] += p;
        P_lds[w][dl * 64 + ((((dj >> 3) ^ (dl & 7)) << 3) | (dj & 7))] = bfc(p);
      }
    }

    // O += P @ V (P per-wave swizzled LDS; V^T swizzled)
    #pragma unroll
    for (int ks = 0; ks < 2; ++ks) {
      bf16x8 ap = *(const bf16x8*)&P_lds[w][q15 * 64 + (((ks * 4 + quad) ^ (q15 & 7)) << 3)];
      #pragma unroll
      for (int db = 0; db < 4; ++db) {
        bf16x8 bv = read_swz(&Vbuf[cur][0], db * 16 + q15, ks * 4 + quad);
        o[db] = __builtin_amdgcn_mfma_f32_16x16x32_bf16(ap, bv, o[db], 0, 0, 0);
      }
    }
  }

  // l: reduce across the 16 lanes of each quad group
  #pragma unroll
  for (int r = 0; r < 4; ++r) {
    #pragma unroll
    for (int off = 1; off < 16; off <<= 1)
      l_i[r] += __shfl_xor(l_i[r], off, 64);
    l_i[r] = 1.f / (l_i[r] + 1e-30f);
  }

  const int b = bh >> 4, h = bh & 15;
  #pragma unroll
  for (int db = 0; db < 4; ++db)
    #pragma unroll
    for (int r = 0; r < 4; ++r) {
      int row = ib + quad * 4 + r;
      ao[((size_t)(b * 1024 + row)) * 1024 + h * 64 + db * 16 + q15] =
          bfc(o[db][r] * l_i[r]);
    }
}

// ---------------- GEMM out = ao @ WoT^T + bo (f32 out), 128x64 tiles -------
__global__ __launch_bounds__(256)
void gemm_out(const unsigned short* __restrict__ A,
              const unsigned short* __restrict__ Bt,
              const unsigned short* __restrict__ bias,
              float* __restrict__ fo) {
  __shared__ __align__(16) unsigned short As[128][32];
  __shared__ __align__(16) unsigned short Bs[64][32];
  const int tid  = threadIdx.x;
  const int lane = tid & 63, w = tid >> 6;
  const int q15  = lane & 15, quad = lane >> 4;
  const int m0 = blockIdx.y * 128, n0 = blockIdx.x * 64;
  const int K = 1024, N = 1024;
  const int lrow = lane >> 2, lkc = (lane & 3) * 8;

  f32x4 acc[2][4] = {};
  for (int k0 = 0; k0 < K; k0 += 32) {
    __syncthreads();
    #pragma unroll
    for (int t = 0; t < 2; ++t) {
      int r0 = w * 32 + t * 16;
      load_lds16(&A[(size_t)(m0 + r0 + lrow) * K + k0 + lkc], &As[r0][0]);
    }
    load_lds16(&Bt[(size_t)(n0 + w * 16 + lrow) * K + k0 + lkc], &Bs[w * 16][0]);
    __syncthreads();
    bf16x8 af[2], bfr[4];
    #pragma unroll
    for (int i = 0; i < 2; ++i)
      af[i] = *(const bf16x8*)&As[w * 32 + i * 16 + q15][quad * 8];
    #pragma unroll
    for (int j = 0; j < 4; ++j)
      bfr[j] = *(const bf16x8*)&Bs[j * 16 + q15][quad * 8];
    #pragma unroll
    for (int i = 0; i < 2; ++i)
      #pragma unroll
      for (int j = 0; j < 4; ++j)
        acc[i][j] = __builtin_amdgcn_mfma_f32_16x16x32_bf16(af[i], bfr[j], acc[i][j], 0, 0, 0);
  }
  #pragma unroll
  for (int i = 0; i < 2; ++i)
    #pragma unroll
    for (int j = 0; j < 4; ++j)
      #pragma unroll
      for (int r = 0; r < 4; ++r) {
        int row = m0 + w * 32 + i * 16 + quad * 4 + r;
        int col = n0 + j * 16 + q15;
        fo[(size_t)row * N + col] = acc[i][j][r] + bf2f(bias[col]);
      }
}

// ---------------------------------------------------------------------------
extern "C" void kernel_launch(void* const* d_in, const int* in_sizes, int n_in,
                              void* d_out, int out_size, void* d_ws, size_t ws_size,
                              hipStream_t stream) {
  (void)in_sizes; (void)n_in; (void)out_size; (void)ws_size;
  const float* x   = (const float*)d_in[0];
  const float* Wq  = (const float*)d_in[1];
  const float* Wkv = (const float*)d_in[2];
  const float* Wo  = (const float*)d_in[3];
  const float* bo  = (const float*)d_in[4];
  const float* rel = (const float*)d_in[5];
  float* out = (float*)d_out;

  unsigned short* ws = (unsigned short*)d_ws;
  unsigned short* WoT   = ws;                      // 1,048,576
  unsigned short* relb  = WoT   + 1048576;         // 65,664 reserved
  unsigned short* bob   = relb  + 65664;           // 1,088 reserved
  unsigned short* q_ws  = bob   + 1088;            // 2,097,152
  unsigned short* k_ws  = q_ws  + 2097152;         // 2,097,152
  unsigned short* vT    = k_ws  + 2097152;         // 2,097,152
  unsigned short* WqkvT = vT    + 2097152;         // 3,145,728 (dead after gemm_qkv)
  unsigned short* xb    = WqkvT + 3145728;         // 2,097,152 (dead after gemm_qkv)
  unsigned short* ao    = WqkvT;                   // alias

  prep_k<<<6210, 256, 0, stream>>>(x, rel, bo, Wq, Wkv, Wo,
                                   xb, relb, bob, WqkvT, WoT);
  gemm_qkv<<<dim3(24, 16), 256, 0, stream>>>(xb, WqkvT, q_ws, k_ws, vT);
  flash_attn<<<dim3(32, 16), 256, 0, stream>>>(q_ws, k_ws, vT, relb, ao);
  gemm_out<<<dim3(16, 16), 256, 0, stream>>>(ao, WoT, bob, out);
}

// Round 11
// 170.825 us; speedup vs baseline: 1.1297x; 1.1002x over previous
//
#include <hip/hip_runtime.h>

typedef __bf16 bf16x8 __attribute__((ext_vector_type(8)));
typedef float f32x4 __attribute__((ext_vector_type(4)));

#define DEV __device__ __forceinline__

DEV unsigned short f2bf(float f) {
  union { float f; unsigned u; } x; x.f = f;
  unsigned r = x.u + 0x7FFFu + ((x.u >> 16) & 1u);  // RNE
  return (unsigned short)(r >> 16);
}
DEV float bf2f(unsigned short h) {
  union { unsigned u; float f; } x; x.u = ((unsigned)h) << 16;
  return x.f;
}
DEV unsigned short bfc(float f) {  // hw cvt (RNE) — hot-loop variant
  union { __bf16 b; unsigned short u; } c; c.b = (__bf16)f; return c.u;
}

typedef __attribute__((address_space(3))) void* lds_vp;
typedef const __attribute__((address_space(1))) void* gbl_vp;
DEV void load_lds16(const unsigned short* gp, void* lp) {
  __builtin_amdgcn_global_load_lds((gbl_vp)(const void*)gp, (lds_vp)lp, 16, 0, 0);
}

// ---- fused ingest (inputs f32): convert x/rel/bo, transpose Wq|Wkv|Wo -----
__global__ __launch_bounds__(256)
void prep_k(const float* __restrict__ x, const float* __restrict__ rel,
            const float* __restrict__ bo, const float* __restrict__ Wq,
            const float* __restrict__ Wkv, const float* __restrict__ Wo,
            unsigned short* __restrict__ xb, unsigned short* __restrict__ relb,
            unsigned short* __restrict__ bob, unsigned short* __restrict__ WqkvT,
            unsigned short* __restrict__ WoT) {
  __shared__ unsigned short tile[32][33];
  const int bid = blockIdx.x, tid = threadIdx.x;
  if (bid < 2114) {
    const float* src; unsigned short* dst; long base; long n;
    if (bid < 2048)      { src = x;   dst = xb;   base = (long)bid * 1024;          n = 2097152; }
    else if (bid < 2113) { src = rel; dst = relb; base = (long)(bid - 2048) * 1024; n = 65600; }
    else                 { src = bo;  dst = bob;  base = 0;                          n = 1024; }
    long i = base + tid * 4;
    if (i < n) {
      float4 v = *(const float4*)&src[i];
      unsigned long long u = (unsigned long long)f2bf(v.x)
                           | ((unsigned long long)f2bf(v.y) << 16)
                           | ((unsigned long long)f2bf(v.z) << 32)
                           | ((unsigned long long)f2bf(v.w) << 48);
      *(unsigned long long*)&dst[i] = u;
    }
  } else {
    int id = bid - 2114;
    const float* src; unsigned short* dst; const int R = 1024; int C, txt, tyt;
    if (id < 1024)      { src = Wq;  dst = WqkvT;           C = 1024; txt = id & 31; tyt = id >> 5; }
    else if (id < 3072) { int l = id - 1024; src = Wkv; dst = WqkvT + 1048576; C = 2048; txt = l & 63; tyt = l >> 6; }
    else                { int l = id - 3072; src = Wo;  dst = WoT;             C = 1024; txt = l & 31; tyt = l >> 5; }
    int c0 = txt * 32, r0 = tyt * 32;
    int tx = tid & 31, ty = tid >> 5;
    #pragma unroll
    for (int i = 0; i < 4; ++i)
      tile[ty + i * 8][tx] = f2bf(src[(size_t)(r0 + ty + i * 8) * C + c0 + tx]);
    __syncthreads();
    #pragma unroll
    for (int i = 0; i < 4; ++i)
      dst[(size_t)(c0 + ty + i * 8) * R + r0 + tx] = tile[tx][ty + i * 8];
  }
}

// ---------------- GEMM qkv = x @ WqkvT^T — 64x128 tiles, 768 blocks --------
// q: *0.125, [b,h,n,d]; k: [b,h,n,d]; v: transposed in-kernel -> vT[b,h,d,n].
// 3 blocks/CU (vs 1.5 at 128x128): latency-bound regime, block overlap wins.
__global__ __launch_bounds__(256)
void gemm_qkv(const unsigned short* __restrict__ A,
              const unsigned short* __restrict__ Bt,
              unsigned short* __restrict__ o0,   // q [b,h,n,d]
              unsigned short* __restrict__ o1,   // k [b,h,n,d]
              unsigned short* __restrict__ o2) { // vT [b,h,d,n]
  __shared__ __align__(16) unsigned short As[64][32];
  __shared__ __align__(16) unsigned short Bs[128][32];
  __shared__ unsigned short tbuf[64][68];   // v-transpose staging
  const int tid  = threadIdx.x;
  const int lane = tid & 63, wave = tid >> 6;
  const int q15  = lane & 15, quad = lane >> 4;
  const int wr = wave >> 1, wc = wave & 1;
  const int m0 = blockIdx.y * 64, n0 = blockIdx.x * 128;
  const int K = 1024;
  const int lrow = lane >> 2, lkc = (lane & 3) * 8;

  f32x4 acc[2][4] = {};
  for (int k0 = 0; k0 < K; k0 += 32) {
    __syncthreads();
    load_lds16(&A[(size_t)(m0 + wave * 16 + lrow) * K + k0 + lkc], &As[wave * 16][0]);
    #pragma unroll
    for (int t = 0; t < 2; ++t)
      load_lds16(&Bt[(size_t)(n0 + wave * 32 + t * 16 + lrow) * K + k0 + lkc],
                 &Bs[wave * 32 + t * 16][0]);
    __syncthreads();
    bf16x8 af[2], bfr[4];
    #pragma unroll
    for (int i = 0; i < 2; ++i)
      af[i] = *(const bf16x8*)&As[wr * 32 + i * 16 + q15][quad * 8];
    #pragma unroll
    for (int j = 0; j < 4; ++j)
      bfr[j] = *(const bf16x8*)&Bs[wc * 64 + j * 16 + q15][quad * 8];
    #pragma unroll
    for (int i = 0; i < 2; ++i)
      #pragma unroll
      for (int j = 0; j < 4; ++j)
        acc[i][j] = __builtin_amdgcn_mfma_f32_16x16x32_bf16(af[i], bfr[j], acc[i][j], 0, 0, 0);
  }

  const int b = m0 >> 10, nn0 = m0 & 1023;
  if (n0 < 2048) {
    // q / k epilogue (tile never straddles the q/k boundary: n0 % 128 == 0)
    #pragma unroll
    for (int i = 0; i < 2; ++i)
      #pragma unroll
      for (int j = 0; j < 4; ++j)
        #pragma unroll
        for (int r = 0; r < 4; ++r) {
          int row = m0 + wr * 32 + i * 16 + quad * 4 + r;
          int col = n0 + wc * 64 + j * 16 + q15;
          float v = acc[i][j][r];
          int nn = row & 1023;
          unsigned short* dst; int c = col; float sc = 1.f;
          if (col < 1024) { dst = o0; sc = 0.125f; }
          else            { dst = o1; c = col - 1024; }
          int h = c >> 6, dd = c & 63;
          dst[((size_t)((row >> 10) * 16 + h) * 1024 + nn) * 64 + dd] = f2bf(v * sc);
        }
  } else {
    // v epilogue: 64 tokens x 2 heads; per head transpose via LDS -> vT
    const int hp = (n0 - 2048) >> 6;
    #pragma unroll
    for (int hh = 0; hh < 2; ++hh) {
      __syncthreads();
      if (wc == hh) {
        #pragma unroll
        for (int i = 0; i < 2; ++i)
          #pragma unroll
          for (int j = 0; j < 4; ++j)
            #pragma unroll
            for (int r = 0; r < 4; ++r)
              tbuf[wr * 32 + i * 16 + quad * 4 + r][j * 16 + q15] = f2bf(acc[i][j][r]);
      }
      __syncthreads();
      // cooperative coalesced store: 64 d x 64 n
      const int bh = b * 16 + hp + hh;
      const int d = tid >> 2, nb = (tid & 3) * 16;
      #pragma unroll
      for (int s = 0; s < 2; ++s) {
        int n = nb + s * 8;
        union { uint4 v; unsigned short us[8]; } t;
        #pragma unroll
        for (int e = 0; e < 8; ++e) t.us[e] = tbuf[n + e][d];
        *(uint4*)&o2[((size_t)bh * 64 + d) * 1024 + nn0 + n] = t.v;
      }
    }
  }
}

// ---- swizzled tile staging: [64 rows][64 shorts], chunk ^= row&7 ----------
DEV void stage16(const unsigned short* gbase, size_t gstride,
                 unsigned short* lbase, int r0, int lane) {
  #pragma unroll
  for (int t = 0; t < 2; ++t) {
    int r = r0 + t * 8 + (lane >> 3);
    int lc = (lane & 7) ^ (r & 7);
    load_lds16(&gbase[(size_t)r * gstride + lc * 8], &lbase[(size_t)(r0 + t * 8) * 64]);
  }
}
DEV bf16x8 read_swz(const unsigned short* buf, int row, int lc) {
  int pc = lc ^ (row & 7);
  return *(const bf16x8*)&buf[row * 64 + pc * 8];
}

// ---------------- flash attention: dbuf, f32 LDS-T (stride 84), XOR-P ------
// (unchanged from R10 — 53 µs, locally converged)
__global__ __launch_bounds__(256)
void flash_attn(const unsigned short* __restrict__ q_ws,   // pre-scaled .125
                const unsigned short* __restrict__ k_ws,
                const unsigned short* __restrict__ vt_ws,  // [bh][64][1024]
                const unsigned short* __restrict__ rel,    // [1025][64]
                unsigned short* __restrict__ ao) {         // [2048][1024]
  __shared__ __align__(16) unsigned short Kbuf[2][64 * 64];
  __shared__ __align__(16) unsigned short Vbuf[2][64 * 64];
  __shared__ __align__(16) unsigned short P_lds[4][16 * 64];  // XOR-8 swizzled
  __shared__ __align__(16) float T_lds[4][16][84];            // f32 band

  const int tid  = threadIdx.x;
  const int lane = tid & 63, w = tid >> 6;
  const int q15  = lane & 15, quad = lane >> 4;
  const int bh = blockIdx.x;
  const int ib = blockIdx.y * 64 + w * 16;

  const unsigned short* qp = q_ws  + (size_t)bh * 1024 * 64;
  const unsigned short* kp = k_ws  + (size_t)bh * 1024 * 64;
  const unsigned short* tp = vt_ws + (size_t)bh * 64 * 1024;

  bf16x8 aq[2];
  #pragma unroll
  for (int ks = 0; ks < 2; ++ks)
    aq[ks] = *(const bf16x8*)&qp[(size_t)(ib + q15) * 64 + ks * 32 + quad * 8];

  f32x4 o[4] = {};
  float l_i[4] = {0.f, 0.f, 0.f, 0.f};

  stage16(kp, 64, &Kbuf[0][0], w * 16, lane);
  stage16(tp, 1024, &Vbuf[0][0], w * 16, lane);

  for (int jt = 0; jt < 16; ++jt) {
    const int j0 = jt * 64, cur = jt & 1;
    __syncthreads();
    if (jt + 1 < 16) {
      stage16(kp + (size_t)(j0 + 64) * 64, 64, &Kbuf[cur ^ 1][0], w * 16, lane);
      stage16(tp + (j0 + 64), 1024, &Vbuf[cur ^ 1][0], w * 16, lane);
    }

    f32x4 accS[4] = {};
    #pragma unroll
    for (int ks = 0; ks < 2; ++ks)
      #pragma unroll
      for (int cb = 0; cb < 4; ++cb) {
        bf16x8 bk = read_swz(&Kbuf[cur][0], cb * 16 + q15, ks * 4 + quad);
        accS[cb] = __builtin_amdgcn_mfma_f32_16x16x32_bf16(aq[ks], bk, accS[cb], 0, 0, 0);
      }
    int tb = ib - j0 + 512 - 63;
    f32x4 accT[5] = {};
    #pragma unroll
    for (int ks = 0; ks < 2; ++ks)
      #pragma unroll
      for (int ub = 0; ub < 5; ++ub) {
        int trow = tb + ub * 16 + q15;
        trow = trow < 0 ? 0 : (trow > 1024 ? 1024 : trow);
        bf16x8 br = *(const bf16x8*)&rel[(size_t)trow * 64 + ks * 32 + quad * 8];
        accT[ub] = __builtin_amdgcn_mfma_f32_16x16x32_bf16(aq[ks], br, accT[ub], 0, 0, 0);
      }
    #pragma unroll
    for (int ub = 0; ub < 5; ++ub)
      #pragma unroll
      for (int r = 0; r < 4; ++r)
        T_lds[w][quad * 4 + r][ub * 16 + q15] = accT[ub][r];

    #pragma unroll
    for (int r = 0; r < 4; ++r) {
      const int dl = quad * 4 + r;
      #pragma unroll
      for (int cb = 0; cb < 4; ++cb) {
        int dj = cb * 16 + q15;
        float s = accS[cb][r] + T_lds[w][dl][63 + dl - dj];
        float p = exp2f(fmaf(s, 1.44269504f, -64.f));
        l_i[r] += p;
        P_lds[w][dl * 64 + ((((dj >> 3) ^ (dl & 7)) << 3) | (dj & 7))] = bfc(p);
      }
    }

    #pragma unroll
    for (int ks = 0; ks < 2; ++ks) {
      bf16x8 ap = *(const bf16x8*)&P_lds[w][q15 * 64 + (((ks * 4 + quad) ^ (q15 & 7)) << 3)];
      #pragma unroll
      for (int db = 0; db < 4; ++db) {
        bf16x8 bv = read_swz(&Vbuf[cur][0], db * 16 + q15, ks * 4 + quad);
        o[db] = __builtin_amdgcn_mfma_f32_16x16x32_bf16(ap, bv, o[db], 0, 0, 0);
      }
    }
  }

  #pragma unroll
  for (int r = 0; r < 4; ++r) {
    #pragma unroll
    for (int off = 1; off < 16; off <<= 1)
      l_i[r] += __shfl_xor(l_i[r], off, 64);
    l_i[r] = 1.f / (l_i[r] + 1e-30f);
  }

  const int b = bh >> 4, h = bh & 15;
  #pragma unroll
  for (int db = 0; db < 4; ++db)
    #pragma unroll
    for (int r = 0; r < 4; ++r) {
      int row = ib + quad * 4 + r;
      ao[((size_t)(b * 1024 + row)) * 1024 + h * 64 + db * 16 + q15] =
          bfc(o[db][r] * l_i[r]);
    }
}

// ---------------- GEMM out = ao @ WoT^T + bo — 64x64 tiles, 512 blocks -----
__global__ __launch_bounds__(256)
void gemm_out(const unsigned short* __restrict__ A,
              const unsigned short* __restrict__ Bt,
              const unsigned short* __restrict__ bias,
              float* __restrict__ fo) {
  __shared__ __align__(16) unsigned short As[64][32];
  __shared__ __align__(16) unsigned short Bs[64][32];
  const int tid  = threadIdx.x;
  const int lane = tid & 63, w = tid >> 6;
  const int q15  = lane & 15, quad = lane >> 4;
  const int m0 = blockIdx.y * 64, n0 = blockIdx.x * 64;
  const int K = 1024, N = 1024;
  const int lrow = lane >> 2, lkc = (lane & 3) * 8;

  f32x4 acc[4] = {};
  for (int k0 = 0; k0 < K; k0 += 32) {
    __syncthreads();
    load_lds16(&A[(size_t)(m0 + w * 16 + lrow) * K + k0 + lkc], &As[w * 16][0]);
    load_lds16(&Bt[(size_t)(n0 + w * 16 + lrow) * K + k0 + lkc], &Bs[w * 16][0]);
    __syncthreads();
    bf16x8 af = *(const bf16x8*)&As[w * 16 + q15][quad * 8];
    bf16x8 bfr[4];
    #pragma unroll
    for (int j = 0; j < 4; ++j)
      bfr[j] = *(const bf16x8*)&Bs[j * 16 + q15][quad * 8];
    #pragma unroll
    for (int j = 0; j < 4; ++j)
      acc[j] = __builtin_amdgcn_mfma_f32_16x16x32_bf16(af, bfr[j], acc[j], 0, 0, 0);
  }
  #pragma unroll
  for (int j = 0; j < 4; ++j)
    #pragma unroll
    for (int r = 0; r < 4; ++r) {
      int row = m0 + w * 16 + quad * 4 + r;
      int col = n0 + j * 16 + q15;
      fo[(size_t)row * N + col] = acc[j][r] + bf2f(bias[col]);
    }
}

// ---------------------------------------------------------------------------
extern "C" void kernel_launch(void* const* d_in, const int* in_sizes, int n_in,
                              void* d_out, int out_size, void* d_ws, size_t ws_size,
                              hipStream_t stream) {
  (void)in_sizes; (void)n_in; (void)out_size; (void)ws_size;
  const float* x   = (const float*)d_in[0];
  const float* Wq  = (const float*)d_in[1];
  const float* Wkv = (const float*)d_in[2];
  const float* Wo  = (const float*)d_in[3];
  const float* bo  = (const float*)d_in[4];
  const float* rel = (const float*)d_in[5];
  float* out = (float*)d_out;

  unsigned short* ws = (unsigned short*)d_ws;
  unsigned short* WoT   = ws;                      // 1,048,576
  unsigned short* relb  = WoT   + 1048576;         // 65,664 reserved
  unsigned short* bob   = relb  + 65664;           // 1,088 reserved
  unsigned short* q_ws  = bob   + 1088;            // 2,097,152
  unsigned short* k_ws  = q_ws  + 2097152;         // 2,097,152
  unsigned short* vT    = k_ws  + 2097152;         // 2,097,152
  unsigned short* WqkvT = vT    + 2097152;         // 3,145,728 (dead after gemm_qkv)
  unsigned short* xb    = WqkvT + 3145728;         // 2,097,152 (dead after gemm_qkv)
  unsigned short* ao    = WqkvT;                   // alias

  prep_k<<<6210, 256, 0, stream>>>(x, rel, bo, Wq, Wkv, Wo,
                                   xb, relb, bob, WqkvT, WoT);
  gemm_qkv<<<dim3(24, 32), 256, 0, stream>>>(xb, WqkvT, q_ws, k_ws, vT);
  flash_attn<<<dim3(32, 16), 256, 0, stream>>>(q_ws, k_ws, vT, relb, ao);
  gemm_out<<<dim3(16, 32), 256, 0, stream>>>(ao, WoT, bob, out);
}